// Round 1
// baseline (607.538 us; speedup 1.0000x reference)
//
#include <hip/hip_runtime.h>

#define BATCH   4
#define CIN     64
#define NNODES  4096
#define NEDGES  131072
#define COUT    63

// ---------------- kernel 1: per-node stats (histogram + weighted scatter) ----
__global__ __launch_bounds__(256) void k_stats(const int* __restrict__ src,
                                               const int* __restrict__ dst,
                                               const float* __restrict__ vals,
                                               int* __restrict__ deg,
                                               float* __restrict__ adjsum) {
    int e = blockIdx.x * blockDim.x + threadIdx.x;
    if (e < NEDGES) {
        atomicAdd(&deg[src[e]], 1);
        atomicAdd(&adjsum[dst[e]], vals[e]);
    }
}

// ---------------- kernel 2: exclusive scan of deg (N=4096, one wave) --------
__global__ void k_scan(const int* __restrict__ deg, int* __restrict__ offs,
                       int* __restrict__ cursor) {
    int lane = threadIdx.x;          // 64 threads, 1 wave
    int base = lane * 64;
    int s = 0;
    for (int i = 0; i < 64; ++i) s += deg[base + i];
    int incl = s;
#pragma unroll
    for (int d = 1; d < 64; d <<= 1) {
        int v = __shfl_up(incl, d, 64);
        if (lane >= d) incl += v;
    }
    int run = incl - s;              // exclusive prefix of this lane's chunk
    for (int i = 0; i < 64; ++i) {
        offs[base + i] = run;
        cursor[base + i] = run;
        run += deg[base + i];
    }
    if (lane == 63) offs[NNODES] = run;   // == NEDGES
}

// ---------------- kernel 3: scatter edges into CSR-by-src -------------------
__global__ __launch_bounds__(256) void k_scatter(const int* __restrict__ src,
                                                 const int* __restrict__ dst,
                                                 int* __restrict__ cursor,
                                                 int* __restrict__ csr) {
    int e = blockIdx.x * blockDim.x + threadIdx.x;
    if (e < NEDGES) {
        int pos = atomicAdd(&cursor[src[e]], 1);
        csr[pos] = dst[e];
    }
}

// ---------------- kernel 4: transpose x (b,c,n) -> xT (b,n,c) ---------------
__global__ __launch_bounds__(256) void k_transpose(const float* __restrict__ x,
                                                   float* __restrict__ xT) {
    __shared__ float tile[64][65];   // 65-pad: bank = (c+n)%32, conflict-free
    int blk = blockIdx.x;            // grid = B * N/64 = 256
    int b = blk >> 6;
    int n0 = (blk & 63) << 6;
    int tx = threadIdx.x & 63, ty = threadIdx.x >> 6;
    const float* xb = x + (size_t)b * CIN * NNODES;
#pragma unroll
    for (int c = ty; c < 64; c += 4)
        tile[c][tx] = xb[(size_t)c * NNODES + n0 + tx];     // coalesced read
    __syncthreads();
    float* xTb = xT + ((size_t)b * NNODES + n0) * 64;
#pragma unroll
    for (int n = ty; n < 64; n += 4)
        xTb[(size_t)n * 64 + tx] = tile[tx][n];             // coalesced write
}

// ---------------- kernel 5: neighbor aggregation (no atomics) ---------------
// one wave per (node, batch); lane = channel. xT rows are 256B coalesced.
__global__ __launch_bounds__(256) void k_aggregate(const float* __restrict__ xT,
                                                   const int* __restrict__ offs,
                                                   const int* __restrict__ csr,
                                                   float* __restrict__ agg) {
    int gtid = blockIdx.x * blockDim.x + threadIdx.x;
    int wid = gtid >> 6;
    int lane = gtid & 63;
    int n = wid >> 2;                // B = 4
    int b = wid & 3;
    if (n >= NNODES) return;
    int k0 = offs[n], k1 = offs[n + 1];
    const float* xb = xT + (size_t)b * NNODES * 64 + lane;
    float acc = 0.f;
    for (int k = k0; k < k1; ++k) {
        int d = csr[k];
        acc += xb[(size_t)d * 64];
    }
    agg[((size_t)b * NNODES + n) * 64 + lane] = acc;
}

// ---------------- kernel 6: fused dual-GEMM + epilogue ----------------------
// block = 256 threads handles (b, 64-node tile). Each thread: 4o x 4n subtile.
__global__ __launch_bounds__(256) void k_final(const float* __restrict__ x,
                                               const float* __restrict__ agg,
                                               const int* __restrict__ deg,
                                               const float* __restrict__ adjsum,
                                               const float* __restrict__ W,
                                               const float* __restrict__ bias,
                                               float* __restrict__ out) {
    __shared__ float w0s[64][64];    // [c][o], o=63 column zeroed
    __shared__ float w1s[64][64];
    __shared__ float degs[64], adjs[64], rden[64], bs[64];

    int blk = blockIdx.x;            // grid = B * N/64 = 256
    int b = blk >> 6;
    int n0 = (blk & 63) << 6;
    int tid = threadIdx.x;

    if (tid < 64) {
        int n = n0 + tid;
        float dg = (float)deg[n];
        float s = adjsum[n];
        degs[tid] = dg;
        adjs[tid] = s;
        rden[tid] = 1.f / ((s == 0.f) ? 1.f : s);
        bs[tid]  = (tid < COUT) ? bias[tid] : 0.f;
    }
    // stage W: o per lane -> LDS write bank = o%32, conflict-free
    for (int i = tid; i < 64 * 64; i += 256) {
        int c = i >> 6, o = i & 63;
        float v0 = 0.f, v1 = 0.f;
        if (o < COUT) {
            v0 = W[((size_t)o * CIN + c) * 2 + 0];
            v1 = W[((size_t)o * CIN + c) * 2 + 1];
        }
        w0s[c][o] = v0;
        w1s[c][o] = v1;
    }
    __syncthreads();

    int tn = tid & 15, to = tid >> 4;
    int o0 = to * 4, nl0 = tn * 4;

    const float* xbase = x + (size_t)b * CIN * NNODES + n0 + nl0;
    const float* abase = agg + ((size_t)b * NNODES + n0 + nl0) * 64;

    float acc0[4][4] = {};           // W0 . x
    float acc1[4][4] = {};           // W1 . agg

#pragma unroll
    for (int c4 = 0; c4 < 64; c4 += 4) {
        // agg rows: contiguous in c -> float4 per ni, reused for 4 c's
        float am[4][4];
#pragma unroll
        for (int ni = 0; ni < 4; ++ni) {
            float4 av = *reinterpret_cast<const float4*>(&abase[(size_t)ni * 64 + c4]);
            am[ni][0] = av.x; am[ni][1] = av.y; am[ni][2] = av.z; am[ni][3] = av.w;
        }
#pragma unroll
        for (int cc = 0; cc < 4; ++cc) {
            int c = c4 + cc;
            float4 xv = *reinterpret_cast<const float4*>(&xbase[(size_t)c * NNODES]);
            float4 w0 = *reinterpret_cast<const float4*>(&w0s[c][o0]);
            float4 w1 = *reinterpret_cast<const float4*>(&w1s[c][o0]);
            float xa[4]  = {xv.x, xv.y, xv.z, xv.w};
            float w0a[4] = {w0.x, w0.y, w0.z, w0.w};
            float w1a[4] = {w1.x, w1.y, w1.z, w1.w};
#pragma unroll
            for (int oi = 0; oi < 4; ++oi) {
#pragma unroll
                for (int ni = 0; ni < 4; ++ni) {
                    acc0[oi][ni] += w0a[oi] * xa[ni];
                    acc1[oi][ni] += w1a[oi] * am[ni][cc];
                }
            }
        }
    }

    // epilogue: y = (deg*(acc0+bias) + acc1) / denom ; channel 63 = counts
#pragma unroll
    for (int oi = 0; oi < 4; ++oi) {
        int o = o0 + oi;
        float rv[4];
#pragma unroll
        for (int ni = 0; ni < 4; ++ni) {
            int nl = nl0 + ni;
            if (o < COUT)
                rv[ni] = (degs[nl] * (acc0[oi][ni] + bs[o]) + acc1[oi][ni]) * rden[nl];
            else
                rv[ni] = adjs[nl];
        }
        float4 r;
        r.x = rv[0]; r.y = rv[1]; r.z = rv[2]; r.w = rv[3];
        *reinterpret_cast<float4*>(&out[((size_t)(b * 64 + o)) * NNODES + n0 + nl0]) = r;
    }
}

// ---------------- launcher --------------------------------------------------
extern "C" void kernel_launch(void* const* d_in, const int* in_sizes, int n_in,
                              void* d_out, int out_size, void* d_ws, size_t ws_size,
                              hipStream_t stream) {
    const float* x    = (const float*)d_in[0];
    const int*   adj  = (const int*)d_in[1];
    const float* vals = (const float*)d_in[2];
    const float* W    = (const float*)d_in[3];
    const float* bias = (const float*)d_in[4];
    float* out = (float*)d_out;

    const int* src = adj;
    const int* dst = adj + NEDGES;

    char* ws = (char*)d_ws;
    // layout: xT 4MB | agg 4MB | deg 16K | adjsum 16K | offs 32K | cursor 16K | csr 512K
    float* xT     = (float*)(ws);
    float* agg    = (float*)(ws + (4 << 20));
    int*   deg    = (int*)  (ws + (8 << 20));
    float* adjsum = (float*)(ws + (8 << 20) + (16 << 10));
    int*   offs   = (int*)  (ws + (8 << 20) + (32 << 10));
    int*   cursor = (int*)  (ws + (8 << 20) + (64 << 10));
    int*   csr    = (int*)  (ws + (8 << 20) + (96 << 10));

    // zero deg + adjsum (contiguous 32KB); everything else is fully overwritten
    hipMemsetAsync(ws + (8 << 20), 0, 32 << 10, stream);

    k_stats    <<<(NEDGES + 255) / 256, 256, 0, stream>>>(src, dst, vals, deg, adjsum);
    k_transpose<<<BATCH * (NNODES / 64), 256, 0, stream>>>(x, xT);
    k_scan     <<<1, 64, 0, stream>>>(deg, offs, cursor);
    k_scatter  <<<(NEDGES + 255) / 256, 256, 0, stream>>>(src, dst, cursor, csr);
    k_aggregate<<<(NNODES * BATCH * 64) / 256, 256, 0, stream>>>(xT, offs, csr, agg);
    k_final    <<<BATCH * (NNODES / 64), 256, 0, stream>>>(x, agg, deg, adjsum, W, bias, out);
}

// Round 2
// 110.220 us; speedup vs baseline: 5.5121x; 5.5121x over previous
//
#include <hip/hip_runtime.h>

#define BATCH   4
#define CIN     64
#define NNODES  4096
#define NEDGES  131072
#define COUT    63

// ---------------- kernel 1: per-node stats (histogram + weighted scatter) ----
__global__ __launch_bounds__(256) void k_stats(const int* __restrict__ src,
                                               const int* __restrict__ dst,
                                               const float* __restrict__ vals,
                                               int* __restrict__ deg,
                                               float* __restrict__ adjsum) {
    int e = blockIdx.x * blockDim.x + threadIdx.x;
    if (e < NEDGES) {
        atomicAdd(&deg[src[e]], 1);
        atomicAdd(&adjsum[dst[e]], vals[e]);
    }
}

// ---------------- kernel 2: exclusive scan of deg (N=4096, one wave) --------
__global__ void k_scan(const int* __restrict__ deg, int* __restrict__ offs,
                       int* __restrict__ cursor) {
    int lane = threadIdx.x;          // 64 threads, 1 wave
    int base = lane * 64;
    int s = 0;
    for (int i = 0; i < 64; ++i) s += deg[base + i];
    int incl = s;
#pragma unroll
    for (int d = 1; d < 64; d <<= 1) {
        int v = __shfl_up(incl, d, 64);
        if (lane >= d) incl += v;
    }
    int run = incl - s;              // exclusive prefix of this lane's chunk
    for (int i = 0; i < 64; ++i) {
        offs[base + i] = run;
        cursor[base + i] = run;
        run += deg[base + i];
    }
    if (lane == 63) offs[NNODES] = run;   // == NEDGES
}

// ---------------- kernel 3: scatter edges into CSR-by-src -------------------
__global__ __launch_bounds__(256) void k_scatter(const int* __restrict__ src,
                                                 const int* __restrict__ dst,
                                                 int* __restrict__ cursor,
                                                 int* __restrict__ csr) {
    int e = blockIdx.x * blockDim.x + threadIdx.x;
    if (e < NEDGES) {
        int pos = atomicAdd(&cursor[src[e]], 1);
        csr[pos] = dst[e];
    }
}

// ---------------- kernel 4: transpose x (b,c,n) -> xT (b,n,c) ---------------
__global__ __launch_bounds__(256) void k_transpose(const float* __restrict__ x,
                                                   float* __restrict__ xT) {
    __shared__ float tile[64][65];   // 65-pad: conflict-free transpose
    int blk = blockIdx.x;            // grid = B * N/64 = 256
    int b = blk >> 6;
    int n0 = (blk & 63) << 6;
    int tx = threadIdx.x & 63, ty = threadIdx.x >> 6;
    const float* xb = x + (size_t)b * CIN * NNODES;
#pragma unroll
    for (int c = ty; c < 64; c += 4)
        tile[c][tx] = xb[(size_t)c * NNODES + n0 + tx];     // coalesced read
    __syncthreads();
    float* xTb = xT + ((size_t)b * NNODES + n0) * 64;
#pragma unroll
    for (int n = ty; n < 64; n += 4)
        xTb[(size_t)n * 64 + tx] = tile[tx][n];             // coalesced write
}

// ---------------- kernel 5: neighbor aggregation (no atomics) ---------------
// one wave per (node, batch); lane = channel. xT rows are 256B coalesced.
__global__ __launch_bounds__(256) void k_aggregate(const float* __restrict__ xT,
                                                   const int* __restrict__ offs,
                                                   const int* __restrict__ csr,
                                                   float* __restrict__ agg) {
    int gtid = blockIdx.x * blockDim.x + threadIdx.x;
    int wid = gtid >> 6;
    int lane = gtid & 63;
    int n = wid >> 2;                // B = 4
    int b = wid & 3;
    if (n >= NNODES) return;
    int k0 = offs[n], k1 = offs[n + 1];
    const float* xb = xT + (size_t)b * NNODES * 64 + lane;
    float acc = 0.f;
    for (int k = k0; k < k1; ++k) {
        int d = csr[k];
        acc += xb[(size_t)d * 64];
    }
    agg[((size_t)b * NNODES + n) * 64 + lane] = acc;
}

// ---------------- kernel 6: fused dual-GEMM + epilogue ----------------------
// block = 256 threads handles (b, 64-node tile). Each thread: 4o x 4n subtile.
// Register-pressure-bounded: unroll 1 on K-loop, VGPR capped at 128.
__global__ __launch_bounds__(256, 4) void k_final(const float* __restrict__ xT,
                                                  const float* __restrict__ agg,
                                                  const int* __restrict__ deg,
                                                  const float* __restrict__ adjsum,
                                                  const float* __restrict__ W,
                                                  const float* __restrict__ bias,
                                                  float* __restrict__ out) {
    __shared__ float w0s[64][64];    // [c][o], o=63 column zeroed
    __shared__ float w1s[64][64];
    __shared__ float degs[64], adjs[64], rden[64], bs[64];

    int blk = blockIdx.x;            // grid = B * N/64 = 256
    int b = blk >> 6;
    int n0 = (blk & 63) << 6;
    int tid = threadIdx.x;

    if (tid < 64) {
        int n = n0 + tid;
        float dg = (float)deg[n];
        float s = adjsum[n];
        degs[tid] = dg;
        adjs[tid] = s;
        rden[tid] = 1.f / ((s == 0.f) ? 1.f : s);
        bs[tid]  = (tid < COUT) ? bias[tid] : 0.f;
    }
    for (int i = tid; i < 64 * 64; i += 256) {
        int c = i >> 6, o = i & 63;
        float v0 = 0.f, v1 = 0.f;
        if (o < COUT) {
            v0 = W[((size_t)o * CIN + c) * 2 + 0];
            v1 = W[((size_t)o * CIN + c) * 2 + 1];
        }
        w0s[c][o] = v0;
        w1s[c][o] = v1;
    }
    __syncthreads();

    int tn = tid & 15, to = tid >> 4;
    int o0 = to * 4, nl0 = tn * 4;

    // both operands from (b,n,c) layout: contiguous 16B row loads
    const float* xb = xT  + ((size_t)b * NNODES + n0 + nl0) * 64;
    const float* ab = agg + ((size_t)b * NNODES + n0 + nl0) * 64;

    float acc0[4][4] = {};           // W0 . x
    float acc1[4][4] = {};           // W1 . agg

#pragma unroll 1
    for (int c4 = 0; c4 < 64; c4 += 4) {
        float xm[4][4], am[4][4];
#pragma unroll
        for (int ni = 0; ni < 4; ++ni) {
            float4 xv = *reinterpret_cast<const float4*>(&xb[(size_t)ni * 64 + c4]);
            float4 av = *reinterpret_cast<const float4*>(&ab[(size_t)ni * 64 + c4]);
            xm[ni][0] = xv.x; xm[ni][1] = xv.y; xm[ni][2] = xv.z; xm[ni][3] = xv.w;
            am[ni][0] = av.x; am[ni][1] = av.y; am[ni][2] = av.z; am[ni][3] = av.w;
        }
#pragma unroll
        for (int cc = 0; cc < 4; ++cc) {
            float4 w0 = *reinterpret_cast<const float4*>(&w0s[c4 + cc][o0]);
            float4 w1 = *reinterpret_cast<const float4*>(&w1s[c4 + cc][o0]);
            float w0a[4] = {w0.x, w0.y, w0.z, w0.w};
            float w1a[4] = {w1.x, w1.y, w1.z, w1.w};
#pragma unroll
            for (int oi = 0; oi < 4; ++oi) {
#pragma unroll
                for (int ni = 0; ni < 4; ++ni) {
                    acc0[oi][ni] += w0a[oi] * xm[ni][cc];
                    acc1[oi][ni] += w1a[oi] * am[ni][cc];
                }
            }
        }
    }

    // epilogue: y = (deg*(acc0+bias) + acc1) / denom ; channel 63 = counts
#pragma unroll
    for (int oi = 0; oi < 4; ++oi) {
        int o = o0 + oi;
        float rv[4];
#pragma unroll
        for (int ni = 0; ni < 4; ++ni) {
            int nl = nl0 + ni;
            if (o < COUT)
                rv[ni] = (degs[nl] * (acc0[oi][ni] + bs[o]) + acc1[oi][ni]) * rden[nl];
            else
                rv[ni] = adjs[nl];
        }
        float4 r;
        r.x = rv[0]; r.y = rv[1]; r.z = rv[2]; r.w = rv[3];
        *reinterpret_cast<float4*>(&out[((size_t)(b * 64 + o)) * NNODES + n0 + nl0]) = r;
    }
}

// ---------------- launcher --------------------------------------------------
extern "C" void kernel_launch(void* const* d_in, const int* in_sizes, int n_in,
                              void* d_out, int out_size, void* d_ws, size_t ws_size,
                              hipStream_t stream) {
    const float* x    = (const float*)d_in[0];
    const int*   adj  = (const int*)d_in[1];
    const float* vals = (const float*)d_in[2];
    const float* W    = (const float*)d_in[3];
    const float* bias = (const float*)d_in[4];
    float* out = (float*)d_out;

    const int* src = adj;
    const int* dst = adj + NEDGES;

    char* ws = (char*)d_ws;
    // layout: xT 4MB | agg 4MB | deg 16K | adjsum 16K | offs 32K | cursor 16K | csr 512K
    float* xT     = (float*)(ws);
    float* agg    = (float*)(ws + (4 << 20));
    int*   deg    = (int*)  (ws + (8 << 20));
    float* adjsum = (float*)(ws + (8 << 20) + (16 << 10));
    int*   offs   = (int*)  (ws + (8 << 20) + (32 << 10));
    int*   cursor = (int*)  (ws + (8 << 20) + (64 << 10));
    int*   csr    = (int*)  (ws + (8 << 20) + (96 << 10));

    // zero deg + adjsum (contiguous 32KB); everything else is fully overwritten
    hipMemsetAsync(ws + (8 << 20), 0, 32 << 10, stream);

    k_stats    <<<(NEDGES + 255) / 256, 256, 0, stream>>>(src, dst, vals, deg, adjsum);
    k_transpose<<<BATCH * (NNODES / 64), 256, 0, stream>>>(x, xT);
    k_scan     <<<1, 64, 0, stream>>>(deg, offs, cursor);
    k_scatter  <<<(NEDGES + 255) / 256, 256, 0, stream>>>(src, dst, cursor, csr);
    k_aggregate<<<(NNODES * BATCH * 64) / 256, 256, 0, stream>>>(xT, offs, csr, agg);
    k_final    <<<BATCH * (NNODES / 64), 256, 0, stream>>>(xT, agg, deg, adjsum, W, bias, out);
}

// Round 4
// 78.160 us; speedup vs baseline: 7.7730x; 1.4102x over previous
//
#include <hip/hip_runtime.h>

#define BATCH   4
#define CIN     64
#define NNODES  4096
#define NEDGES  131072
#define COUT    63

// ---------------- kernel 1: transpose x (b,c,n) -> xT (n,b,c) + zero stats --
// Runs FIRST: also zeroes deg/adjsum so no hipMemsetAsync node is needed.
__global__ __launch_bounds__(256) void k_transpose(const float* __restrict__ x,
                                                   float* __restrict__ xT,
                                                   int* __restrict__ deg,
                                                   float* __restrict__ adjsum) {
    int blk = blockIdx.x;            // grid = B * N/64 = 256
    int tid = threadIdx.x;
    int gtid = blk * 256 + tid;
    if (gtid < NNODES) deg[gtid] = 0;
    else if (gtid < 2 * NNODES) adjsum[gtid - NNODES] = 0.f;

    __shared__ float tile[64][65];   // 65-pad: conflict-free transpose
    int b = blk >> 6;
    int n0 = (blk & 63) << 6;
    int tx = tid & 63, ty = tid >> 6;
    const float* xb = x + (size_t)b * CIN * NNODES;
#pragma unroll
    for (int c = ty; c < 64; c += 4)
        tile[c][tx] = xb[(size_t)c * NNODES + n0 + tx];     // coalesced read
    __syncthreads();
#pragma unroll
    for (int n = ty; n < 64; n += 4)                         // 256B/row writes
        xT[((size_t)(n0 + n) * BATCH + b) * 64 + tx] = tile[tx][n];
}

// ---------------- kernel 2: per-node stats (histogram + weighted scatter) ---
__global__ __launch_bounds__(256) void k_stats(const int* __restrict__ src,
                                               const int* __restrict__ dst,
                                               const float* __restrict__ vals,
                                               int* __restrict__ deg,
                                               float* __restrict__ adjsum) {
    int e = blockIdx.x * blockDim.x + threadIdx.x;
    if (e < NEDGES) {
        atomicAdd(&deg[src[e]], 1);
        atomicAdd(&adjsum[dst[e]], vals[e]);
    }
}

// ---------------- kernel 3: exclusive scan of deg (256 threads) -------------
__global__ __launch_bounds__(256) void k_scan(const int* __restrict__ deg,
                                              int* __restrict__ offs,
                                              int* __restrict__ cursor) {
    int tid = threadIdx.x;
    int lane = tid & 63, wave = tid >> 6;
    int base = tid * 16;
    int vals[16];
    int s = 0;
#pragma unroll
    for (int i = 0; i < 16; i += 4) {
        int4 v = *reinterpret_cast<const int4*>(&deg[base + i]);
        vals[i] = v.x; vals[i + 1] = v.y; vals[i + 2] = v.z; vals[i + 3] = v.w;
        s += v.x + v.y + v.z + v.w;
    }
    int incl = s;
#pragma unroll
    for (int d = 1; d < 64; d <<= 1) {
        int v = __shfl_up(incl, d, 64);
        if (lane >= d) incl += v;
    }
    __shared__ int wsum[4];
    if (lane == 63) wsum[wave] = incl;
    __syncthreads();
    int run = incl - s;              // exclusive prefix within wave
    for (int w = 0; w < wave; ++w) run += wsum[w];
#pragma unroll
    for (int i = 0; i < 16; i += 4) {
        int4 o;
        o.x = run; run += vals[i];
        o.y = run; run += vals[i + 1];
        o.z = run; run += vals[i + 2];
        o.w = run; run += vals[i + 3];
        *reinterpret_cast<int4*>(&offs[base + i]) = o;
        *reinterpret_cast<int4*>(&cursor[base + i]) = o;
    }
    if (tid == 255) offs[NNODES] = run;   // == NEDGES
}

// ---------------- kernel 4: scatter edges into CSR-by-src -------------------
__global__ __launch_bounds__(256) void k_scatter(const int* __restrict__ src,
                                                 const int* __restrict__ dst,
                                                 int* __restrict__ cursor,
                                                 int* __restrict__ csr) {
    int e = blockIdx.x * blockDim.x + threadIdx.x;
    if (e < NEDGES) {
        int pos = atomicAdd(&cursor[src[e]], 1);
        csr[pos] = dst[e];
    }
}

// ---------------- kernel 5: neighbor aggregation (no atomics) ---------------
// one wave per node, all 4 batches at once: each neighbor row is a contiguous
// 1KB wave transaction (64 lanes x float4). Unroll-4 for memory-level parallelism.
__global__ __launch_bounds__(256) void k_aggregate(const float* __restrict__ xT,
                                                   const int* __restrict__ offs,
                                                   const int* __restrict__ csr,
                                                   float* __restrict__ agg) {
    int gtid = blockIdx.x * 256 + threadIdx.x;
    int n = gtid >> 6;
    int lane = gtid & 63;
    if (n >= NNODES) return;
    int k0 = offs[n], k1 = offs[n + 1];
    const float* xb = xT + (size_t)lane * 4;
    float4 acc = make_float4(0.f, 0.f, 0.f, 0.f);
    int k = k0;
    for (; k + 4 <= k1; k += 4) {
        int d0 = csr[k], d1 = csr[k + 1], d2 = csr[k + 2], d3 = csr[k + 3];
        float4 v0 = *reinterpret_cast<const float4*>(xb + (size_t)d0 * 256);
        float4 v1 = *reinterpret_cast<const float4*>(xb + (size_t)d1 * 256);
        float4 v2 = *reinterpret_cast<const float4*>(xb + (size_t)d2 * 256);
        float4 v3 = *reinterpret_cast<const float4*>(xb + (size_t)d3 * 256);
        acc.x += (v0.x + v1.x) + (v2.x + v3.x);
        acc.y += (v0.y + v1.y) + (v2.y + v3.y);
        acc.z += (v0.z + v1.z) + (v2.z + v3.z);
        acc.w += (v0.w + v1.w) + (v2.w + v3.w);
    }
    for (; k < k1; ++k) {
        int d = csr[k];
        float4 v = *reinterpret_cast<const float4*>(xb + (size_t)d * 256);
        acc.x += v.x; acc.y += v.y; acc.z += v.z; acc.w += v.w;
    }
    *reinterpret_cast<float4*>(agg + (size_t)n * 256 + lane * 4) = acc;
}

// ---------------- kernel 6: fused dual-GEMM + epilogue ----------------------
// block = 256 threads handles (b, 64-node tile). Each thread: 4o x 4n subtile.
__global__ __launch_bounds__(256, 4) void k_final(const float* __restrict__ xT,
                                                  const float* __restrict__ agg,
                                                  const int* __restrict__ deg,
                                                  const float* __restrict__ adjsum,
                                                  const float* __restrict__ W,
                                                  const float* __restrict__ bias,
                                                  float* __restrict__ out) {
    __shared__ float w0s[64][64];    // [c][o], o=63 column zeroed
    __shared__ float w1s[64][64];
    __shared__ float degs[64], adjs[64], rden[64], bs[64];

    int blk = blockIdx.x;            // grid = B * N/64 = 256
    int b = blk >> 6;
    int n0 = (blk & 63) << 6;
    int tid = threadIdx.x;

    if (tid < 64) {
        int n = n0 + tid;
        float dg = (float)deg[n];
        float s = adjsum[n];
        degs[tid] = dg;
        adjs[tid] = s;
        rden[tid] = 1.f / ((s == 0.f) ? 1.f : s);
        bs[tid]  = (tid < COUT) ? bias[tid] : 0.f;
    }
    for (int i = tid; i < 64 * 64; i += 256) {
        int c = i >> 6, o = i & 63;
        float v0 = 0.f, v1 = 0.f;
        if (o < COUT) {
            v0 = W[((size_t)o * CIN + c) * 2 + 0];
            v1 = W[((size_t)o * CIN + c) * 2 + 1];
        }
        w0s[c][o] = v0;
        w1s[c][o] = v1;
    }
    __syncthreads();

    int tn = tid & 15, to = tid >> 4;
    int o0 = to * 4, nl0 = tn * 4;

    // (n,b,c) layout: node row stride = 256 floats, batch slice = +b*64
    const float* xb = xT  + ((size_t)(n0 + nl0) * BATCH + b) * 64;
    const float* ab = agg + ((size_t)(n0 + nl0) * BATCH + b) * 64;

    float acc0[4][4] = {};           // W0 . x
    float acc1[4][4] = {};           // W1 . agg

#pragma unroll 1
    for (int c4 = 0; c4 < 64; c4 += 4) {
        float xm[4][4], am[4][4];
#pragma unroll
        for (int ni = 0; ni < 4; ++ni) {
            float4 xv = *reinterpret_cast<const float4*>(&xb[(size_t)ni * 256 + c4]);
            float4 av = *reinterpret_cast<const float4*>(&ab[(size_t)ni * 256 + c4]);
            xm[ni][0] = xv.x; xm[ni][1] = xv.y; xm[ni][2] = xv.z; xm[ni][3] = xv.w;
            am[ni][0] = av.x; am[ni][1] = av.y; am[ni][2] = av.z; am[ni][3] = av.w;
        }
#pragma unroll
        for (int cc = 0; cc < 4; ++cc) {
            float4 w0 = *reinterpret_cast<const float4*>(&w0s[c4 + cc][o0]);
            float4 w1 = *reinterpret_cast<const float4*>(&w1s[c4 + cc][o0]);
            float w0a[4] = {w0.x, w0.y, w0.z, w0.w};
            float w1a[4] = {w1.x, w1.y, w1.z, w1.w};
#pragma unroll
            for (int oi = 0; oi < 4; ++oi) {
#pragma unroll
                for (int ni = 0; ni < 4; ++ni) {
                    acc0[oi][ni] += w0a[oi] * xm[ni][cc];
                    acc1[oi][ni] += w1a[oi] * am[ni][cc];
                }
            }
        }
    }

    // epilogue: y = (deg*(acc0+bias) + acc1) / denom ; channel 63 = counts
#pragma unroll
    for (int oi = 0; oi < 4; ++oi) {
        int o = o0 + oi;
        float rv[4];
#pragma unroll
        for (int ni = 0; ni < 4; ++ni) {
            int nl = nl0 + ni;
            if (o < COUT)
                rv[ni] = (degs[nl] * (acc0[oi][ni] + bs[o]) + acc1[oi][ni]) * rden[nl];
            else
                rv[ni] = adjs[nl];
        }
        float4 r;
        r.x = rv[0]; r.y = rv[1]; r.z = rv[2]; r.w = rv[3];
        *reinterpret_cast<float4*>(&out[((size_t)(b * 64 + o)) * NNODES + n0 + nl0]) = r;
    }
}

// ---------------- launcher --------------------------------------------------
extern "C" void kernel_launch(void* const* d_in, const int* in_sizes, int n_in,
                              void* d_out, int out_size, void* d_ws, size_t ws_size,
                              hipStream_t stream) {
    const float* x    = (const float*)d_in[0];
    const int*   adj  = (const int*)d_in[1];
    const float* vals = (const float*)d_in[2];
    const float* W    = (const float*)d_in[3];
    const float* bias = (const float*)d_in[4];
    float* out = (float*)d_out;

    const int* src = adj;
    const int* dst = adj + NEDGES;

    char* ws = (char*)d_ws;
    // layout: xT 4MB | agg 4MB | deg 16K | adjsum 16K | offs 32K | cursor 16K | csr 512K
    float* xT     = (float*)(ws);
    float* agg    = (float*)(ws + (4 << 20));
    int*   deg    = (int*)  (ws + (8 << 20));
    float* adjsum = (float*)(ws + (8 << 20) + (16 << 10));
    int*   offs   = (int*)  (ws + (8 << 20) + (32 << 10));
    int*   cursor = (int*)  (ws + (8 << 20) + (64 << 10));
    int*   csr    = (int*)  (ws + (8 << 20) + (96 << 10));

    k_transpose<<<BATCH * (NNODES / 64), 256, 0, stream>>>(x, xT, deg, adjsum);
    k_stats    <<<(NEDGES + 255) / 256, 256, 0, stream>>>(src, dst, vals, deg, adjsum);
    k_scan     <<<1, 256, 0, stream>>>(deg, offs, cursor);
    k_scatter  <<<(NEDGES + 255) / 256, 256, 0, stream>>>(src, dst, cursor, csr);
    k_aggregate<<<(NNODES * 64) / 256, 256, 0, stream>>>(xT, offs, csr, agg);
    k_final    <<<BATCH * (NNODES / 64), 256, 0, stream>>>(xT, agg, deg, adjsum, W, bias, out);
}